// Round 7
// baseline (46.889 us; speedup 1.0000x reference)
//
#include <hip/hip_runtime.h>
#include <math.h>

#define BB 32
#define TT 128
#define NTOK 30
#define DD 512
#define C2F 2.885390081777927f   // 2*log2(e): tanh(x) = 1 - 2/(1+2^(C2F*x))

typedef unsigned short u16;
typedef __attribute__((ext_vector_type(8))) short bf16x8;
typedef __attribute__((ext_vector_type(8))) unsigned short u16x8;
typedef __attribute__((ext_vector_type(4))) float f32x4;

__device__ __forceinline__ u16 f2bf(float f) {
    unsigned u = __builtin_bit_cast(unsigned, f);
    u += 0x7fffu + ((u >> 16) & 1u);          // RNE
    return (u16)(u >> 16);
}
__device__ __forceinline__ float bf2f(u16 u) {
    return __builtin_bit_cast(float, (unsigned)u << 16);
}

__device__ __forceinline__ void load_lds16(const u16* g, u16* l) {
    __builtin_amdgcn_global_load_lds(
        (const __attribute__((address_space(1))) unsigned int*)g,
        (__attribute__((address_space(3))) unsigned int*)l,
        16, 0, 0);
}

// cross-lane sum over 64 lanes: 4 DPP steps (VALU pipe) + 2 shfl
template<int CTRL>
__device__ __forceinline__ float dpp_add(float x) {
    int yi = __builtin_amdgcn_update_dpp(0, __builtin_bit_cast(int, x), CTRL, 0xF, 0xF, true);
    return x + __builtin_bit_cast(float, yi);
}
__device__ __forceinline__ float red64(float x) {
    x = dpp_add<0xB1>(x);    // quad_perm xor1
    x = dpp_add<0x4E>(x);    // quad_perm xor2
    x = dpp_add<0x141>(x);   // row_half_mirror
    x = dpp_add<0x140>(x);   // row_mirror
    x += __shfl_xor(x, 16, 64);
    x += __shfl_xor(x, 32, 64);
    return x;
}

// ---------------- prep: W [K][N] f32 -> W^T [N][K] bf16 (weights only) ----------------
__global__ __launch_bounds__(256) void prep(
    const float* __restrict__ W_S, const float* __restrict__ W_V,
    u16* __restrict__ WtS, u16* __restrict__ WtV)
{
    __shared__ u16 tile[32][33];
    int idx = blockIdx.x;
    const float* W = (idx & 256) ? W_V : W_S;
    u16*        T  = (idx & 256) ? WtV : WtS;
    idx &= 255;
    int k0 = (idx >> 4) * 32, n0 = (idx & 15) * 32;
    int c = threadIdx.x & 31, r8 = threadIdx.x >> 5;
    #pragma unroll
    for (int q = 0; q < 4; ++q) {
        int k = r8 + q * 8;
        tile[k][c] = f2bf(W[(size_t)(k0 + k) * DD + n0 + c]);
    }
    __syncthreads();
    #pragma unroll
    for (int q = 0; q < 4; ++q) {
        int n = r8 + q * 8;
        T[(size_t)(n0 + n) * DD + k0 + c] = tile[c][n];
    }
}

// ---------------- bf16 MFMA GEMM, dbuf pipeline (prefetch AFTER barrier) ---------------
// A = raw f32 activations (cast to bf16 in reg-staging); B = W^T bf16 via global_load_lds.
// Y (bf16) = (A @ W + bias) * C2F.   by==0 S-blocks also export bf16 A tile -> Abf_s.
// 512 threads = 8 waves (2 m x 4 n), block tile 64x64, BK=64, 8 K-steps.
// Race-freedom: all prefetch for tile t+1 (a-regs AND B-DMA into ldsB[(t+1)&1]) is issued
// AFTER __syncthreads()(t); reads of that buffer (tile t-1) completed before that barrier.
// __syncthreads() = s_waitcnt vmcnt(0) lgkmcnt(0) + s_barrier: tile t fully landed, no
// counted-vmcnt fragility.
__global__ __launch_bounds__(512) void gemm_mfma(
    const float* __restrict__ h_s, const float* __restrict__ h_v,
    const u16* __restrict__ WtS, const u16* __restrict__ WtV,
    const float* __restrict__ b_S, const float* __restrict__ b_V,
    u16* __restrict__ Sbf, u16* __restrict__ Vbf, u16* __restrict__ Abf_s)
{
    __shared__ u16 ldsA[2][64 * 64];
    __shared__ u16 ldsB[2][64 * 64];
    const int bid = blockIdx.x;
    const int grp = bid >> 6, rem = bid & 63;
    const int by  = rem >> 3;
    const int bxx = grp * 8 + (rem & 7);       // panel-sharing blocks: same bid%8 -> same XCD
    if (bxx >= 15 + 64) return;                // 8 pad blocks (no barrier executed)
    const float* A; const u16* Bt; const float* bias; u16* Y; int bm;
    if (bxx < 15) { A = h_s; Bt = WtS; bias = b_S; Y = Sbf; bm = bxx * 64; }
    else          { A = h_v; Bt = WtV; bias = b_V; Y = Vbf; bm = (bxx - 15) * 64; }
    const int bn = by * 64;
    const bool wrA = (bxx < 15) && (by == 0);  // export bf16 h_s tile once

    const int tid  = threadIdx.x;
    const int lane = tid & 63;
    const int wid  = tid >> 6;                 // 0..7
    const int wr = wid >> 2, wc = wid & 3;     // 2 x 4 wave grid; wave tile 32m x 16n

    // staging slot: row = tid>>3 (0..63), logical chunk lc = tid&7, swizzled chunk lc^(row&7)
    const int srow = tid >> 3, slc = tid & 7;
    const int ssc  = slc ^ (srow & 7);
    const float* gA = A + (size_t)(bm + srow) * DD + slc * 8;          // f32, logical
    const u16*   gB = Bt + (size_t)(bn + srow) * DD + ssc * 8;         // bf16, pre-swizzled src
    u16* wAp[2] = { &ldsA[0][srow * 64 + ssc * 8], &ldsA[1][srow * 64 + ssc * 8] };
    u16* wBp[2] = { &ldsB[0][wid * 512],           &ldsB[1][wid * 512] };
    u16* expA = Abf_s + (size_t)(bm + srow) * DD + slc * 8;            // logical layout

    const int arow = wr * 32 + (lane & 15);    // + i*16
    const int brow = wc * 16 + (lane & 15);
    const int kq   = lane >> 4;
    const int sw   = lane & 7;                 // == row&7 for all fragment rows

    f32x4 acc[2];
    acc[0] = (f32x4){0.f, 0.f, 0.f, 0.f};
    acc[1] = (f32x4){0.f, 0.f, 0.f, 0.f};

    // prologue: tile 0 in flight
    float4 a0 = *(const float4*)(gA);
    float4 a1 = *(const float4*)(gA + 4);
    load_lds16(gB, wBp[0]);

    for (int t = 0; t < 8; ++t) {
        const int cur = t & 1;
        // cvt + swizzled LDS write of A tile t (compiler waits the a-reg loads)
        bf16x8 p;
        p[0]=(short)f2bf(a0.x); p[1]=(short)f2bf(a0.y); p[2]=(short)f2bf(a0.z); p[3]=(short)f2bf(a0.w);
        p[4]=(short)f2bf(a1.x); p[5]=(short)f2bf(a1.y); p[6]=(short)f2bf(a1.z); p[7]=(short)f2bf(a1.w);
        *(bf16x8*)wAp[cur] = p;
        if (wrA) *(bf16x8*)(expA + t * 64) = p;             // export bf16 h_s

        __syncthreads();    // tile t fully staged (vmcnt0+lgkm0); reads of buf cur^1 retired

        if (t < 7) {                                        // prefetch t+1 (safe: after barrier)
            a0 = *(const float4*)(gA + (t + 1) * 64);
            a1 = *(const float4*)(gA + (t + 1) * 64 + 4);
            load_lds16(gB + (t + 1) * 64, wBp[cur ^ 1]);
        }

        bf16x8 af[2][2], bf[2];
        #pragma unroll
        for (int s = 0; s < 2; ++s) {
            #pragma unroll
            for (int i = 0; i < 2; ++i) {
                int ra = arow + i * 16;
                af[i][s] = *(const bf16x8*)(&ldsA[cur][ra * 64 + ((s * 4 + kq) ^ sw) * 8]);
            }
            bf[s] = *(const bf16x8*)(&ldsB[cur][brow * 64 + ((s * 4 + kq) ^ sw) * 8]);
        }
        #pragma unroll
        for (int s = 0; s < 2; ++s)
            #pragma unroll
            for (int i = 0; i < 2; ++i)
                acc[i] = __builtin_amdgcn_mfma_f32_16x16x32_bf16(af[i][s], bf[s], acc[i], 0, 0, 0);
    }

    // D layout: col = lane&15, row = (lane>>4)*4 + reg
    #pragma unroll
    for (int i = 0; i < 2; ++i) {
        int r = bm + wr * 32 + i * 16 + (lane >> 4) * 4;
        int c = bn + wc * 16 + (lane & 15);
        float bv = bias[c];
        #pragma unroll
        for (int reg = 0; reg < 4; ++reg)
            Y[(size_t)(r + reg) * DD + c] = f2bf((acc[i][reg] + bv) * C2F);
    }
}

// ---------------- attend: block = (b, 8 t's), wave per t, 8 d per lane ----------------
// S and H (bf16 h_s, from gemm export) staged once; single barrier.
__global__ __launch_bounds__(512) void attend4(
    const u16* __restrict__ Sbf, const u16* __restrict__ Vbf,
    const u16* __restrict__ Hbf, const int* __restrict__ lengths,
    const float* __restrict__ W_w, const float* __restrict__ b_w,
    float* __restrict__ out)
{
    __shared__ u16 Sl[NTOK * DD];                // 30720 B
    __shared__ u16 Hl[NTOK * DD];                // 30720 B
    const int b  = blockIdx.x >> 4;
    const int tc = blockIdx.x & 15;
    const int tid  = threadIdx.x;
    const int w    = tid >> 6;                   // wave = local t (0..7)
    const int lane = tid & 63;
    const int t_glob = tc * 8 + w;
    const int len = lengths[b];
    const int d0 = lane * 8;
    const float bwv = b_w[0];

    // stage S[b] and H[b] (both bf16): 1920 16B chunks each
    {
        const uint4* sS = (const uint4*)(Sbf + (size_t)b * NTOK * DD);
        const uint4* sH = (const uint4*)(Hbf + (size_t)b * NTOK * DD);
        uint4* dS = (uint4*)Sl;
        uint4* dH = (uint4*)Hl;
        #pragma unroll
        for (int i = 0; i < 4; ++i) {
            int idx = i * 512 + tid;
            if (idx < NTOK * DD / 8) { dS[idx] = sS[idx]; dH[idx] = sH[idx]; }
        }
    }

    // V row (bf16, pre-scaled) and W_w (f32) into regs
    float v[8], ww[8];
    {
        u16x8 v8 = *(const u16x8*)(Vbf + ((size_t)(b * TT + t_glob)) * DD + d0);
        float4 w0 = *(const float4*)&W_w[d0];
        float4 w1 = *(const float4*)&W_w[d0 + 4];
        #pragma unroll
        for (int j = 0; j < 8; ++j) v[j] = bf2f(v8[j]);
        ww[0]=w0.x; ww[1]=w0.y; ww[2]=w0.z; ww[3]=w0.w;
        ww[4]=w1.x; ww[5]=w1.y; ww[6]=w1.z; ww[7]=w1.w;
    }
    float wpart = 0.f;
    #pragma unroll
    for (int j = 0; j < 8; ++j) wpart += ww[j];
    const float wsum = red64(wpart);

    __syncthreads();

    // beta partials: pacc[n] = sum_d w_d * rcp(1 + 2^(S'+V'))
    float pacc[NTOK];
    #pragma unroll
    for (int n = 0; n < NTOK; ++n) {
        u16x8 s8 = *(const u16x8*)(Sl + n * DD + d0);
        float a = 0.f;
        #pragma unroll
        for (int j = 0; j < 8; ++j) {
            float e = __builtin_amdgcn_exp2f(bf2f(s8[j]) + v[j]);
            a = fmaf(ww[j], __builtin_amdgcn_rcpf(1.f + e), a);
        }
        pacc[n] = red64(a);
    }

    // beta[n] = wsum + b_w - 2*pacc[n]; masked softmax; alpha
    float mx = -1e30f;
    #pragma unroll
    for (int n = 0; n < NTOK; ++n) {
        float bn = fmaf(-2.f, pacc[n], wsum + bwv);
        pacc[n] = bn;
        if (n < len) mx = fmaxf(mx, bn);
    }
    float ssum = 0.f;
    #pragma unroll
    for (int n = 0; n < NTOK; ++n) {
        float e = (n < len) ? __expf(pacc[n] - mx) : 0.f;
        pacc[n] = e;
        ssum += e;
    }
    const float inv = 1.f / (ssum + 1e-13f);
    #pragma unroll
    for (int n = 0; n < NTOK; ++n) pacc[n] = fmaf(pacc[n], inv, 1e-13f);

    // out[t] = sum_n alpha[n] * h_s[n]  (bf16 H from LDS)
    float acc8[8] = {};
    #pragma unroll
    for (int n = 0; n < NTOK; ++n) {
        float a = pacc[n];
        u16x8 h8 = *(const u16x8*)(Hl + n * DD + d0);
        #pragma unroll
        for (int j = 0; j < 8; ++j)
            acc8[j] = fmaf(a, bf2f(h8[j]), acc8[j]);
    }
    float* Or = out + ((size_t)(b * TT + t_glob)) * DD + d0;
    *(float4*)&Or[0] = make_float4(acc8[0], acc8[1], acc8[2], acc8[3]);
    *(float4*)&Or[4] = make_float4(acc8[4], acc8[5], acc8[6], acc8[7]);
}

extern "C" void kernel_launch(void* const* d_in, const int* in_sizes, int n_in,
                              void* d_out, int out_size, void* d_ws, size_t ws_size,
                              hipStream_t stream) {
    const float* h_s     = (const float*)d_in[0];
    const float* h_v     = (const float*)d_in[1];
    const int*   lengths = (const int*)  d_in[2];
    const float* W_S     = (const float*)d_in[3];
    const float* b_S     = (const float*)d_in[4];
    const float* W_V     = (const float*)d_in[5];
    const float* b_V     = (const float*)d_in[6];
    const float* W_w     = (const float*)d_in[7];
    const float* b_w     = (const float*)d_in[8];
    float* out = (float*)d_out;

    // workspace (all bf16): Sbf | Vbf | WtS | WtV | Abf_s
    u16* Sbf   = (u16*)d_ws;                               // 960*512
    u16* Vbf   = Sbf + (size_t)BB * NTOK * DD;             // 4096*512
    u16* WtS   = Vbf + (size_t)BB * TT * DD;               // 512*512
    u16* WtV   = WtS + (size_t)DD * DD;                    // 512*512
    u16* Abf_s = WtV + (size_t)DD * DD;                    // 960*512

    prep<<<512, 256, 0, stream>>>(W_S, W_V, WtS, WtV);
    gemm_mfma<<<640, 512, 0, stream>>>(
        h_s, h_v, WtS, WtV, b_S, b_V, Sbf, Vbf, Abf_s);
    attend4<<<BB * 16, 512, 0, stream>>>(Sbf, Vbf, Abf_s, lengths, W_w, b_w, out);
}